// Round 6
// baseline (546.383 us; speedup 1.0000x reference)
//
#include <hip/hip_runtime.h>
#include <hip/hip_bf16.h>
#include <hip/hip_fp16.h>

#define N_NODES 100000
#define R_REL   7
#define E_EDGES 1600000
#define EDIM    16
#define KTOT    640    // 448 msg + 64 self + 112 F + 7 sw + 9 pad  (B layout, K dim)
#define AROWB   1280   // A-tile row stride in BYTES (640 bf16): 16 rows = 20480B
                       // -> 8 blocks/CU (LDS). Bank conflicts: row-XOR swizzle.
#define CAP     56     // slots per node; P(deg>55 | Binom(1.6M,1e-5)) ~ 4e-10
#define CSTR    16     // cnt stride in ints: one counter per 64B line
#define CHUNK   16     // records gathered per vmcnt-drain window (32 loads in flight)

// swizzle: byte offset within row XOR'd with (row&7)<<4 (16B-block permutation,
// closed within each 128B group). Verified R4.
#define ASWZ(row, cb) ((row) * AROWB + ((cb) ^ (((row) & 7) << 4)))

typedef __bf16 bf16_t;
typedef bf16_t bf16x8 __attribute__((ext_vector_type(8)));
typedef float  f32x4  __attribute__((ext_vector_type(4)));
typedef unsigned long long u64;

#define RFL(v) __builtin_amdgcn_readfirstlane(v)
#define RL(v, l) __builtin_amdgcn_readlane(v, l)

// ---------------- fused prep + scatter (cnt zeroed by hipMemsetAsync) -------
// record (8B): u0 = src(17b) | rel(3b)<<17 | e[0:12)<<20
//              u1 = e[12:21) | (f32(w) & 0xFFFFFE00)

__global__ __launch_bounds__(256) void k_pre(
    const float* __restrict__ x, const int* __restrict__ el,
    const float* __restrict__ wgt,
    const float* __restrict__ W_lin, const float* __restrict__ W_self,
    const float* __restrict__ W_edge, const float* __restrict__ b_edge,
    int* __restrict__ cnt, bf16_t* __restrict__ xb, bf16_t* __restrict__ Bp,
    u64* __restrict__ recs8)
{
    const int t = blockIdx.x * 256 + threadIdx.x;

    // ---- x -> bf16, 16 floats per thread (400000 threads) ----
    if (t < (N_NODES * 64) / 16) {
        const float4* xp = (const float4*)(x + (size_t)t * 16);
        float4 v0 = xp[0], v1 = xp[1], v2 = xp[2], v3 = xp[3];
        bf16x8 o0 = {(bf16_t)v0.x, (bf16_t)v0.y, (bf16_t)v0.z, (bf16_t)v0.w,
                     (bf16_t)v1.x, (bf16_t)v1.y, (bf16_t)v1.z, (bf16_t)v1.w};
        bf16x8 o1 = {(bf16_t)v2.x, (bf16_t)v2.y, (bf16_t)v2.z, (bf16_t)v2.w,
                     (bf16_t)v3.x, (bf16_t)v3.y, (bf16_t)v3.z, (bf16_t)v3.w};
        *(bf16x8*)(xb + (size_t)t * 16)     = o0;
        *(bf16x8*)(xb + (size_t)t * 16 + 8) = o1;
    }

    // ---- pack B (40960 threads) ----
    // B[k][j]: k<448 W_lin[j][k]; 448..511 W_self; 512..623 (W_lin_r@W_edge);
    // 624..630 (W_lin_r@b_edge); 631..639 zero.  Bp[((k/8)*64 + j)*8 + (k%8)]
    if (t < KTOT * 64) {
        int k = t >> 6;
        int j = t & 63;
        float v;
        if (k < 448) {
            v = W_lin[j * 448 + k];
        } else if (k < 512) {
            v = W_self[j * 64 + (k - 448)];
        } else if (k < 624) {
            int r = (k - 512) >> 4, kk = (k - 512) & 15;
            float sacc = 0.f;
            for (int d = 0; d < 64; d++)
                sacc = fmaf(W_lin[j * 448 + r * 64 + d], W_edge[d * 16 + kk], sacc);
            v = sacc;
        } else if (k < 631) {
            int r = k - 624;
            float sacc = 0.f;
            for (int d = 0; d < 64; d++)
                sacc = fmaf(W_lin[j * 448 + r * 64 + d], b_edge[d], sacc);
            v = sacc;
        } else {
            v = 0.f;
        }
        Bp[((k >> 3) * 64 + j) * 8 + (k & 7)] = (bf16_t)v;
    }

    // ---- scatter: 4 edges / thread, int4-coalesced (400000 threads) ----
    if (t < E_EDGES / 4) {
        const int4* ep = (const int4*)(el + (size_t)t * 12);  // t*48B, 16B-aligned
        int4 q0 = ep[0], q1 = ep[1], q2 = ep[2];
        float4 w4 = *(const float4*)(wgt + (size_t)t * 4);
        const int e = t * 4;
        const int srcs[4] = {q0.x, q0.w, q1.z, q2.y};
        const int dsts[4] = {q0.y, q1.x, q1.w, q2.z};
        const int rels[4] = {q0.z, q1.y, q2.x, q2.w};
        const float ws[4] = {w4.x, w4.y, w4.z, w4.w};
        int slot[4];
#pragma unroll
        for (int i = 0; i < 4; i++)
            slot[i] = atomicAdd(&cnt[dsts[i] * CSTR], 1);
#pragma unroll
        for (int i = 0; i < 4; i++) {
            unsigned u0 = (unsigned)srcs[i] | ((unsigned)rels[i] << 17)
                        | ((unsigned)((e + i) & 0xFFF) << 20);
            unsigned u1 = ((unsigned)(e + i) >> 12)
                        | (__float_as_uint(ws[i]) & 0xFFFFFE00u);
            recs8[(size_t)dsts[i] * CAP + slot[i]] = ((u64)u1 << 32) | u0;
        }
    }
}

// ---------------- fused gather/segment-sum + MFMA GEMM ----------------------
// Stage 1: per node, sort records by rel IN-REGISTER (7 ballots ->
// rank = prefix[rel] + mbcnt(group_mask) -> ds_permute), then walk the flat
// rel-sorted stream in CHUNK=16 windows: issue all 32 gathers first, consume
// with progressive vmcnt drain (fmas of record k overlap loads of k+1..15).
// Rel-boundary flushes are scalar-gated overwrites into pre-zeroed LDS rows.
// ~1.5 latency windows per node instead of ~7 serial ballot-group waits.
// launch_bounds min-waves relaxed to 6: avoids forced spills of the CHUNK
// arrays under a 64-VGPR cap; 8 blocks/CU still possible if alloc <= 64.

__global__ __launch_bounds__(256, 6) void k_main(
    const bf16_t* __restrict__ xb, const float* __restrict__ ef,
    const float* __restrict__ b_lin, const float* __restrict__ b_self,
    const int* __restrict__ cnt, const u64* __restrict__ recs8,
    const bf16_t* __restrict__ Bp, float* __restrict__ out)
{
    __shared__ __align__(16) unsigned char A[16 * AROWB];  // 20 KB exactly
    const int wave = threadIdx.x >> 6;
    const int lane = threadIdx.x & 63;
    const int lef  = lane & 15;
    const int nodeBase = blockIdx.x * 16;
    const int n0 = nodeBase + wave * 4;

    // prefetch degrees (scalar via RFL), record windows, self rows; pre-zero
    // all accumulation regions (msg rows bytes 0..895; F/sw/pad 1024..1279).
    int md[4];
    u64 rw[4];
#pragma unroll
    for (int i = 0; i < 4; i++) {
        const int row = wave * 4 + i;
        md[i] = RFL(min(cnt[(n0 + i) * CSTR], CAP));
        rw[i] = (lane < md[i]) ? recs8[(size_t)(n0 + i) * CAP + lane] : 0ull;
        *(bf16_t*)(A + ASWZ(row, (448 + lane) * 2)) = xb[(n0 + i) * 64 + lane];
        uint4 z = {0u, 0u, 0u, 0u};
        if (lane < 56) *(uint4*)(A + ASWZ(row, lane * 16)) = z;
        if (lane < 16) *(uint4*)(A + ASWZ(row, 1024 + lane * 16)) = z;
    }

#pragma unroll
    for (int i = 0; i < 4; i++) {
        const int row = wave * 4 + i;
        const int m = md[i];
        if (m == 0) continue;                        // wave-uniform skip
        const int u0v = (int)(unsigned)rw[i];
        const int u1v = (int)(unsigned)(rw[i] >> 32);
        const int relv = ((unsigned)u0v >> 17) & 7;
        const bool valid = lane < m;

        // ---- in-register sort by rel ----
        u64 g0 = __ballot(valid && relv == 0);
        u64 g1 = __ballot(valid && relv == 1);
        u64 g2 = __ballot(valid && relv == 2);
        u64 g3 = __ballot(valid && relv == 3);
        u64 g4 = __ballot(valid && relv == 4);
        u64 g5 = __ballot(valid && relv == 5);
        u64 g6 = __ballot(valid && relv == 6);
        const int c0 = __builtin_popcountll(g0), c1 = __builtin_popcountll(g1);
        const int c2 = __builtin_popcountll(g2), c3 = __builtin_popcountll(g3);
        const int c4 = __builtin_popcountll(g4), c5 = __builtin_popcountll(g5);
        const int p0 = 0, p1 = c0, p2 = p1 + c1, p3 = p2 + c2;
        const int p4 = p3 + c3, p5 = p4 + c4, p6 = p5 + c5;
        const bool b0 = relv & 1, b1 = relv & 2, b2 = relv & 4;
        u64 t0 = b0 ? g1 : g0, t1 = b0 ? g3 : g2, t2 = b0 ? g5 : g4, t3 = g6;
        u64 sA = b1 ? t1 : t0, sB = b1 ? t3 : t2;
        u64 mm = b2 ? sB : sA;
        int pa = b0 ? p1 : p0, pb = b0 ? p3 : p2, pc = b0 ? p5 : p4, pd = p6;
        int pe_ = b1 ? pb : pa, pf_ = b1 ? pd : pc;
        int pfx = b2 ? pf_ : pe_;
        int rig = __builtin_amdgcn_mbcnt_hi((unsigned)(mm >> 32),
                  __builtin_amdgcn_mbcnt_lo((unsigned)mm, 0));
        int rank = valid ? (pfx + rig) : lane;       // bijective 0..63
        const int su0 = __builtin_amdgcn_ds_permute(rank * 4, u0v);
        const int su1 = __builtin_amdgcn_ds_permute(rank * 4, u1v);

        // ---- chunked issue/consume over the rel-sorted stream ----
        float a = 0.f, F = 0.f, sw_ = 0.f;
        int cur = -1;
        int base = 0;
        while (base < m) {
            const int nk = min(m - base, CHUNK);
            unsigned short xv[CHUNK];
            float ev[CHUNK], wk[CHUNK];
            int rk[CHUNK];
#pragma unroll
            for (int k = 0; k < CHUNK; k++) {
                if (k < nk) {                        // scalar branch
                    const int uu0 = RL(su0, base + k);
                    const int uu1 = RL(su1, base + k);
                    const int src = uu0 & 0x1FFFF;
                    const int e   = (int)(((unsigned)uu0) >> 20)
                                  | ((uu1 & 0x1FF) << 12);
                    rk[k] = (int)((((unsigned)uu0) >> 17) & 7);
                    wk[k] = __uint_as_float((unsigned)uu1 & 0xFFFFFE00u);
                    xv[k] = *(const unsigned short*)(xb + ((size_t)src << 6) + lane);
                    ev[k] = ef[(size_t)e * EDIM + lef];
                }
            }
#pragma unroll
            for (int k = 0; k < CHUNK; k++) {
                if (k < nk) {                        // scalar branch
                    if (rk[k] != cur) {              // scalar: rel boundary
                        if (cur >= 0) {
                            *(bf16_t*)(A + ASWZ(row, (cur * 64 + lane) * 2)) = (bf16_t)a;
                            if (lane < EDIM)
                                *(bf16_t*)(A + ASWZ(row, (512 + cur * EDIM + lane) * 2)) = (bf16_t)F;
                            if (lane == 0)
                                *(bf16_t*)(A + ASWZ(row, (624 + cur) * 2)) = (bf16_t)sw_;
                        }
                        a = 0.f; F = 0.f; sw_ = 0.f; cur = rk[k];
                    }
                    const float xf = __uint_as_float(((unsigned)xv[k]) << 16);
                    a   = fmaf(wk[k], xf,    a);
                    F   = fmaf(wk[k], ev[k], F);
                    sw_ += wk[k];
                }
            }
            base += nk;
        }
        // final flush (m>0 guarantees cur>=0)
        *(bf16_t*)(A + ASWZ(row, (cur * 64 + lane) * 2)) = (bf16_t)a;
        if (lane < EDIM)
            *(bf16_t*)(A + ASWZ(row, (512 + cur * EDIM + lane) * 2)) = (bf16_t)F;
        if (lane == 0)
            *(bf16_t*)(A + ASWZ(row, (624 + cur) * 2)) = (bf16_t)sw_;
    }
    __syncthreads();

    // stage 2: MFMA over K=640 (swizzled A reads; verified R4)
    const int quad = lane >> 4;
    const int l15  = lane & 15;
    const unsigned abase = (unsigned)l15 * AROWB;
    const unsigned aswz  = (unsigned)((l15 & 7) << 4);
    f32x4 c = {0.f, 0.f, 0.f, 0.f};
#pragma unroll
    for (int s2i = 0; s2i < KTOT / 32; s2i++) {
        bf16x8 av = *(const bf16x8*)(A + abase
                     + (((unsigned)(s2i * 64 + quad * 16)) ^ aswz));
        bf16x8 bv = *(const bf16x8*)(Bp + (((s2i * 4 + quad) * 64) + wave * 16 + l15) * 8);
        c = __builtin_amdgcn_mfma_f32_16x16x32_bf16(av, bv, c, 0, 0, 0);
    }
    const int j = wave * 16 + l15;
    const float bias = b_lin[j] + b_self[j];
#pragma unroll
    for (int q = 0; q < 4; q++) {
        const int n = nodeBase + quad * 4 + q;
        float v = c[q] + bias;
        out[n * 64 + j] = v > 0.f ? v : 0.f;
    }
}

// ---------------- launch ----------------------------------------------------

extern "C" void kernel_launch(void* const* d_in, const int* in_sizes, int n_in,
                              void* d_out, int out_size, void* d_ws, size_t ws_size,
                              hipStream_t stream) {
    const float* x      = (const float*)d_in[0];
    const int*   el     = (const int*)  d_in[1];
    const float* wgt    = (const float*)d_in[2];
    const float* ef     = (const float*)d_in[3];
    const float* W_lin  = (const float*)d_in[4];
    const float* b_lin  = (const float*)d_in[5];
    const float* W_self = (const float*)d_in[6];
    const float* b_self = (const float*)d_in[7];
    const float* W_edge = (const float*)d_in[8];
    const float* b_edge = (const float*)d_in[9];
    float* out = (float*)d_out;

    // workspace: recs8(44.8M) | cnt(6.4M padded) | xb(12.8M) | Bp(80K) ~64.1 MB
    u64*    recs8 = (u64*)d_ws;
    int*    cnt   = (int*)(recs8 + (size_t)N_NODES * CAP);
    bf16_t* xb    = (bf16_t*)(cnt + (size_t)N_NODES * CSTR);
    bf16_t* Bp    = xb + (size_t)N_NODES * 64;

    hipMemsetAsync(cnt, 0, (size_t)N_NODES * CSTR * sizeof(int), stream);
    k_pre <<<1563, 256, 0, stream>>>(x, el, wgt, W_lin, W_self, W_edge, b_edge,
                                     cnt, xb, Bp, recs8);
    k_main<<<N_NODES / 16, 256, 0, stream>>>(xb, ef, b_lin, b_self,
                                             cnt, recs8, Bp, out);
}

// Round 7
// 376.568 us; speedup vs baseline: 1.4510x; 1.4510x over previous
//
#include <hip/hip_runtime.h>
#include <hip/hip_bf16.h>
#include <hip/hip_fp16.h>

#define N_NODES 100000
#define R_REL   7
#define E_EDGES 1600000
#define EDIM    16
#define KTOT    640    // 448 msg + 64 self + 112 F + 7 sw + 9 pad  (B layout, K dim)
#define AROWB   1280   // A-tile row stride in BYTES (640 bf16): 16 rows = 20480B
                       // -> 8 blocks/CU (LDS). Bank conflicts: row-XOR swizzle.
#define CAP     56     // slots per node; P(deg>55 | Binom(1.6M,1e-5)) ~ 4e-10
#define CSTR    16     // cnt stride in ints: one counter per 64B line
#define CHUNK   16     // records per vmcnt-drain window; stream PADDED with
                       // (rel=7,w=0) dummies so the unrolled loops have NO
                       // runtime guard -> arrays stay in registers (R6 lesson:
                       // conditional writes demoted them to scratch, 168MB WRITE)

// swizzle: byte offset within row XOR'd with (row&7)<<4 (16B-block permutation,
// closed within each 128B group). Verified R4/R6.
#define ASWZ(row, cb) ((row) * AROWB + ((cb) ^ (((row) & 7) << 4)))

typedef __bf16 bf16_t;
typedef bf16_t bf16x8 __attribute__((ext_vector_type(8)));
typedef float  f32x4  __attribute__((ext_vector_type(4)));
typedef unsigned long long u64;

#define RFL(v) __builtin_amdgcn_readfirstlane(v)
#define RL(v, l) __builtin_amdgcn_readlane(v, l)

// ---------------- fused prep + scatter (cnt zeroed by hipMemsetAsync) -------
// record (8B): u0 = src(17b) | rel(3b)<<17 | e[0:12)<<20
//              u1 = e[12:21) | (f32(w) & 0xFFFFFE00)

__global__ __launch_bounds__(256) void k_pre(
    const float* __restrict__ x, const int* __restrict__ el,
    const float* __restrict__ wgt,
    const float* __restrict__ W_lin, const float* __restrict__ W_self,
    const float* __restrict__ W_edge, const float* __restrict__ b_edge,
    int* __restrict__ cnt, bf16_t* __restrict__ xb, bf16_t* __restrict__ Bp,
    u64* __restrict__ recs8)
{
    const int t = blockIdx.x * 256 + threadIdx.x;

    // ---- x -> bf16, 16 floats per thread (400000 threads) ----
    if (t < (N_NODES * 64) / 16) {
        const float4* xp = (const float4*)(x + (size_t)t * 16);
        float4 v0 = xp[0], v1 = xp[1], v2 = xp[2], v3 = xp[3];
        bf16x8 o0 = {(bf16_t)v0.x, (bf16_t)v0.y, (bf16_t)v0.z, (bf16_t)v0.w,
                     (bf16_t)v1.x, (bf16_t)v1.y, (bf16_t)v1.z, (bf16_t)v1.w};
        bf16x8 o1 = {(bf16_t)v2.x, (bf16_t)v2.y, (bf16_t)v2.z, (bf16_t)v2.w,
                     (bf16_t)v3.x, (bf16_t)v3.y, (bf16_t)v3.z, (bf16_t)v3.w};
        *(bf16x8*)(xb + (size_t)t * 16)     = o0;
        *(bf16x8*)(xb + (size_t)t * 16 + 8) = o1;
    }

    // ---- pack B (40960 threads) ----
    // B[k][j]: k<448 W_lin[j][k]; 448..511 W_self; 512..623 (W_lin_r@W_edge);
    // 624..630 (W_lin_r@b_edge); 631..639 zero.  Bp[((k/8)*64 + j)*8 + (k%8)]
    if (t < KTOT * 64) {
        int k = t >> 6;
        int j = t & 63;
        float v;
        if (k < 448) {
            v = W_lin[j * 448 + k];
        } else if (k < 512) {
            v = W_self[j * 64 + (k - 448)];
        } else if (k < 624) {
            int r = (k - 512) >> 4, kk = (k - 512) & 15;
            float sacc = 0.f;
            for (int d = 0; d < 64; d++)
                sacc = fmaf(W_lin[j * 448 + r * 64 + d], W_edge[d * 16 + kk], sacc);
            v = sacc;
        } else if (k < 631) {
            int r = k - 624;
            float sacc = 0.f;
            for (int d = 0; d < 64; d++)
                sacc = fmaf(W_lin[j * 448 + r * 64 + d], b_edge[d], sacc);
            v = sacc;
        } else {
            v = 0.f;
        }
        Bp[((k >> 3) * 64 + j) * 8 + (k & 7)] = (bf16_t)v;
    }

    // ---- scatter: 4 edges / thread, int4-coalesced (400000 threads) ----
    if (t < E_EDGES / 4) {
        const int4* ep = (const int4*)(el + (size_t)t * 12);  // t*48B, 16B-aligned
        int4 q0 = ep[0], q1 = ep[1], q2 = ep[2];
        float4 w4 = *(const float4*)(wgt + (size_t)t * 4);
        const int e = t * 4;
        const int srcs[4] = {q0.x, q0.w, q1.z, q2.y};
        const int dsts[4] = {q0.y, q1.x, q1.w, q2.z};
        const int rels[4] = {q0.z, q1.y, q2.x, q2.w};
        const float ws[4] = {w4.x, w4.y, w4.z, w4.w};
        int slot[4];
#pragma unroll
        for (int i = 0; i < 4; i++)
            slot[i] = atomicAdd(&cnt[dsts[i] * CSTR], 1);
#pragma unroll
        for (int i = 0; i < 4; i++) {
            unsigned u0 = (unsigned)srcs[i] | ((unsigned)rels[i] << 17)
                        | ((unsigned)((e + i) & 0xFFF) << 20);
            unsigned u1 = ((unsigned)(e + i) >> 12)
                        | (__float_as_uint(ws[i]) & 0xFFFFFE00u);
            recs8[(size_t)dsts[i] * CAP + slot[i]] = ((u64)u1 << 32) | u0;
        }
    }
}

// ---------------- fused gather/segment-sum + MFMA GEMM ----------------------
// Stage 1: per node, sort records by rel IN-REGISTER (7 ballots ->
// rank = prefix[rel] + mbcnt(group_mask) -> ds_permute; logic verified R6).
// Invalid lanes push DUMMY records (rel=7, w=0), so the rel-sorted stream is
// padded to a CHUNK multiple and both unrolled loops run guard-free: all
// array indices compile-time-constant -> registers, no scratch (R6 fix).
// Per CHUNK window: issue 32 gathers, consume with progressive vmcnt drain.
// ~1.5-2 latency windows per node instead of ~7 serial ballot-group waits.

__global__ __launch_bounds__(256, 6) void k_main(
    const bf16_t* __restrict__ xb, const float* __restrict__ ef,
    const float* __restrict__ b_lin, const float* __restrict__ b_self,
    const int* __restrict__ cnt, const u64* __restrict__ recs8,
    const bf16_t* __restrict__ Bp, float* __restrict__ out)
{
    __shared__ __align__(16) unsigned char A[16 * AROWB];  // 20 KB exactly
    const int wave = threadIdx.x >> 6;
    const int lane = threadIdx.x & 63;
    const int lef  = lane & 15;
    const int nodeBase = blockIdx.x * 16;
    const int n0 = nodeBase + wave * 4;

    // prefetch degrees (scalar via RFL), record windows, self rows; pre-zero
    // all accumulation regions (msg rows bytes 0..895; F/sw/pad 1024..1279).
    int md[4];
    u64 rw[4];
#pragma unroll
    for (int i = 0; i < 4; i++) {
        const int row = wave * 4 + i;
        md[i] = RFL(min(cnt[(n0 + i) * CSTR], CAP));
        rw[i] = (lane < md[i]) ? recs8[(size_t)(n0 + i) * CAP + lane] : 0ull;
        *(bf16_t*)(A + ASWZ(row, (448 + lane) * 2)) = xb[(n0 + i) * 64 + lane];
        uint4 z = {0u, 0u, 0u, 0u};
        if (lane < 56) *(uint4*)(A + ASWZ(row, lane * 16)) = z;
        if (lane < 16) *(uint4*)(A + ASWZ(row, 1024 + lane * 16)) = z;
    }

#pragma unroll
    for (int i = 0; i < 4; i++) {
        const int row = wave * 4 + i;
        const int m = md[i];
        if (m == 0) continue;                        // wave-uniform skip
        const int u0v = (int)(unsigned)rw[i];
        const int u1v = (int)(unsigned)(rw[i] >> 32);
        const int relv = ((unsigned)u0v >> 17) & 7;
        const bool valid = lane < m;

        // ---- in-register sort by rel (verified R6) ----
        u64 g0 = __ballot(valid && relv == 0);
        u64 g1 = __ballot(valid && relv == 1);
        u64 g2 = __ballot(valid && relv == 2);
        u64 g3 = __ballot(valid && relv == 3);
        u64 g4 = __ballot(valid && relv == 4);
        u64 g5 = __ballot(valid && relv == 5);
        u64 g6 = __ballot(valid && relv == 6);
        const int c0 = __builtin_popcountll(g0), c1 = __builtin_popcountll(g1);
        const int c2 = __builtin_popcountll(g2), c3 = __builtin_popcountll(g3);
        const int c4 = __builtin_popcountll(g4), c5 = __builtin_popcountll(g5);
        const int p0 = 0, p1 = c0, p2 = p1 + c1, p3 = p2 + c2;
        const int p4 = p3 + c3, p5 = p4 + c4, p6 = p5 + c5;
        const bool b0 = relv & 1, b1 = relv & 2, b2 = relv & 4;
        u64 t0 = b0 ? g1 : g0, t1 = b0 ? g3 : g2, t2 = b0 ? g5 : g4, t3 = g6;
        u64 sA = b1 ? t1 : t0, sB = b1 ? t3 : t2;
        u64 mm = b2 ? sB : sA;
        int pa = b0 ? p1 : p0, pb = b0 ? p3 : p2, pc = b0 ? p5 : p4, pd = p6;
        int pe_ = b1 ? pb : pa, pf_ = b1 ? pd : pc;
        int pfx = b2 ? pf_ : pe_;
        int rig = __builtin_amdgcn_mbcnt_hi((unsigned)(mm >> 32),
                  __builtin_amdgcn_mbcnt_lo((unsigned)mm, 0));
        int rank = valid ? (pfx + rig) : lane;       // bijective 0..63
        // dummy payload for pad positions: rel=7, w=0, src=0, e=0
        const int pv0 = valid ? u0v : (7 << 17);
        const int pv1 = valid ? u1v : 0;
        const int su0 = __builtin_amdgcn_ds_permute(rank * 4, pv0);
        const int su1 = __builtin_amdgcn_ds_permute(rank * 4, pv1);

        // ---- guard-free chunked issue/consume over the padded stream ----
        float a = 0.f, F = 0.f, sw_ = 0.f;
        int cur = -1;
        for (int base = 0; base < m; base += CHUNK) {
            unsigned short xv[CHUNK];
            float ev[CHUNK], wk[CHUNK];
            int rk[CHUNK];
#pragma unroll
            for (int k = 0; k < CHUNK; k++) {        // unconditional: regs
                const int uu0 = RL(su0, base + k);
                const int uu1 = RL(su1, base + k);
                const int src = uu0 & 0x1FFFF;
                const int e   = (int)(((unsigned)uu0) >> 20)
                              | ((uu1 & 0x1FF) << 12);
                rk[k] = (int)((((unsigned)uu0) >> 17) & 7);
                wk[k] = __uint_as_float((unsigned)uu1 & 0xFFFFFE00u);
                xv[k] = *(const unsigned short*)(xb + ((size_t)src << 6) + lane);
                ev[k] = ef[(size_t)e * EDIM + lef];
            }
#pragma unroll
            for (int k = 0; k < CHUNK; k++) {        // unconditional: regs
                if (rk[k] != cur && rk[k] != 7) {    // scalar rel boundary
                    if (cur >= 0) {
                        *(bf16_t*)(A + ASWZ(row, (cur * 64 + lane) * 2)) = (bf16_t)a;
                        if (lane < EDIM)
                            *(bf16_t*)(A + ASWZ(row, (512 + cur * EDIM + lane) * 2)) = (bf16_t)F;
                        if (lane == 0)
                            *(bf16_t*)(A + ASWZ(row, (624 + cur) * 2)) = (bf16_t)sw_;
                    }
                    a = 0.f; F = 0.f; sw_ = 0.f; cur = rk[k];
                }
                const float xf = __uint_as_float(((unsigned)xv[k]) << 16);
                a   = fmaf(wk[k], xf,    a);         // dummies: w=0, exact no-op
                F   = fmaf(wk[k], ev[k], F);
                sw_ += wk[k];
            }
        }
        // final flush (m>0 guarantees cur>=0)
        *(bf16_t*)(A + ASWZ(row, (cur * 64 + lane) * 2)) = (bf16_t)a;
        if (lane < EDIM)
            *(bf16_t*)(A + ASWZ(row, (512 + cur * EDIM + lane) * 2)) = (bf16_t)F;
        if (lane == 0)
            *(bf16_t*)(A + ASWZ(row, (624 + cur) * 2)) = (bf16_t)sw_;
    }
    __syncthreads();

    // stage 2: MFMA over K=640 (swizzled A reads; verified R4/R6)
    const int quad = lane >> 4;
    const int l15  = lane & 15;
    const unsigned abase = (unsigned)l15 * AROWB;
    const unsigned aswz  = (unsigned)((l15 & 7) << 4);
    f32x4 c = {0.f, 0.f, 0.f, 0.f};
#pragma unroll
    for (int s2i = 0; s2i < KTOT / 32; s2i++) {
        bf16x8 av = *(const bf16x8*)(A + abase
                     + (((unsigned)(s2i * 64 + quad * 16)) ^ aswz));
        bf16x8 bv = *(const bf16x8*)(Bp + (((s2i * 4 + quad) * 64) + wave * 16 + l15) * 8);
        c = __builtin_amdgcn_mfma_f32_16x16x32_bf16(av, bv, c, 0, 0, 0);
    }
    const int j = wave * 16 + l15;
    const float bias = b_lin[j] + b_self[j];
#pragma unroll
    for (int q = 0; q < 4; q++) {
        const int n = nodeBase + quad * 4 + q;
        float v = c[q] + bias;
        out[n * 64 + j] = v > 0.f ? v : 0.f;
    }
}

// ---------------- launch ----------------------------------------------------

extern "C" void kernel_launch(void* const* d_in, const int* in_sizes, int n_in,
                              void* d_out, int out_size, void* d_ws, size_t ws_size,
                              hipStream_t stream) {
    const float* x      = (const float*)d_in[0];
    const int*   el     = (const int*)  d_in[1];
    const float* wgt    = (const float*)d_in[2];
    const float* ef     = (const float*)d_in[3];
    const float* W_lin  = (const float*)d_in[4];
    const float* b_lin  = (const float*)d_in[5];
    const float* W_self = (const float*)d_in[6];
    const float* b_self = (const float*)d_in[7];
    const float* W_edge = (const float*)d_in[8];
    const float* b_edge = (const float*)d_in[9];
    float* out = (float*)d_out;

    // workspace: recs8(44.8M) | cnt(6.4M padded) | xb(12.8M) | Bp(80K) ~64.1 MB
    u64*    recs8 = (u64*)d_ws;
    int*    cnt   = (int*)(recs8 + (size_t)N_NODES * CAP);
    bf16_t* xb    = (bf16_t*)(cnt + (size_t)N_NODES * CSTR);
    bf16_t* Bp    = xb + (size_t)N_NODES * 64;

    hipMemsetAsync(cnt, 0, (size_t)N_NODES * CSTR * sizeof(int), stream);
    k_pre <<<1563, 256, 0, stream>>>(x, el, wgt, W_lin, W_self, W_edge, b_edge,
                                     cnt, xb, Bp, recs8);
    k_main<<<N_NODES / 16, 256, 0, stream>>>(xb, ef, b_lin, b_self,
                                             cnt, recs8, Bp, out);
}

// Round 8
// 371.937 us; speedup vs baseline: 1.4690x; 1.0125x over previous
//
#include <hip/hip_runtime.h>
#include <hip/hip_bf16.h>
#include <hip/hip_fp16.h>

#define N_NODES 100000
#define R_REL   7
#define E_EDGES 1600000
#define EDIM    16
#define KTOT    640    // 448 msg + 64 self + 112 F + 7 sw + 9 pad  (B layout, K dim)
#define AROWB   1280   // A-tile row stride in BYTES (640 bf16): 16 rows = 20480B
                       // -> 8 blocks/CU (LDS). Bank conflicts: row-XOR swizzle.
#define CAP     56     // slots per node; P(deg>55 | Binom(1.6M,1e-5)) ~ 4e-10
#define CSTR    16     // cnt stride in ints: one counter per 64B line
#define CHUNK   16     // records per vmcnt-drain window; stream PADDED with
                       // (rel=7,w=0) dummies -> guard-free unrolled loops (R7)

// recs8 layout: SLOT-MAJOR  recs8[slot * N_NODES + dst]
// k_pre stores: at any instant the active slot band is ~3-5 slots (Poisson
// progress, sigma~4) = 2-4MB chip-wide -> L2-resident RMW instead of random
// 64B HBM line fetch+writeback per 8B store (the ~125us k_pre floor).
// k_main reads: one line = same slot of 8 CONSECUTIVE nodes; a block owns 16
// consecutive nodes -> 8x line reuse on window loads.

// swizzle: byte offset within row XOR'd with (row&7)<<4 (verified R4/R6/R7)
#define ASWZ(row, cb) ((row) * AROWB + ((cb) ^ (((row) & 7) << 4)))

typedef __bf16 bf16_t;
typedef bf16_t bf16x8 __attribute__((ext_vector_type(8)));
typedef float  f32x4  __attribute__((ext_vector_type(4)));
typedef unsigned long long u64;

#define RFL(v) __builtin_amdgcn_readfirstlane(v)
#define RL(v, l) __builtin_amdgcn_readlane(v, l)

// ---------------- fused prep + scatter (cnt zeroed by hipMemsetAsync) -------
// record (8B): u0 = src(17b) | rel(3b)<<17 | e[0:12)<<20
//              u1 = e[12:21) | (f32(w) & 0xFFFFFE00)

__global__ __launch_bounds__(256) void k_pre(
    const float* __restrict__ x, const int* __restrict__ el,
    const float* __restrict__ wgt,
    const float* __restrict__ W_lin, const float* __restrict__ W_self,
    const float* __restrict__ W_edge, const float* __restrict__ b_edge,
    int* __restrict__ cnt, bf16_t* __restrict__ xb, bf16_t* __restrict__ Bp,
    u64* __restrict__ recs8)
{
    const int t = blockIdx.x * 256 + threadIdx.x;

    // ---- x -> bf16, 16 floats per thread (400000 threads) ----
    if (t < (N_NODES * 64) / 16) {
        const float4* xp = (const float4*)(x + (size_t)t * 16);
        float4 v0 = xp[0], v1 = xp[1], v2 = xp[2], v3 = xp[3];
        bf16x8 o0 = {(bf16_t)v0.x, (bf16_t)v0.y, (bf16_t)v0.z, (bf16_t)v0.w,
                     (bf16_t)v1.x, (bf16_t)v1.y, (bf16_t)v1.z, (bf16_t)v1.w};
        bf16x8 o1 = {(bf16_t)v2.x, (bf16_t)v2.y, (bf16_t)v2.z, (bf16_t)v2.w,
                     (bf16_t)v3.x, (bf16_t)v3.y, (bf16_t)v3.z, (bf16_t)v3.w};
        *(bf16x8*)(xb + (size_t)t * 16)     = o0;
        *(bf16x8*)(xb + (size_t)t * 16 + 8) = o1;
    }

    // ---- pack B (40960 threads) ----
    // B[k][j]: k<448 W_lin[j][k]; 448..511 W_self; 512..623 (W_lin_r@W_edge);
    // 624..630 (W_lin_r@b_edge); 631..639 zero.  Bp[((k/8)*64 + j)*8 + (k%8)]
    if (t < KTOT * 64) {
        int k = t >> 6;
        int j = t & 63;
        float v;
        if (k < 448) {
            v = W_lin[j * 448 + k];
        } else if (k < 512) {
            v = W_self[j * 64 + (k - 448)];
        } else if (k < 624) {
            int r = (k - 512) >> 4, kk = (k - 512) & 15;
            float sacc = 0.f;
            for (int d = 0; d < 64; d++)
                sacc = fmaf(W_lin[j * 448 + r * 64 + d], W_edge[d * 16 + kk], sacc);
            v = sacc;
        } else if (k < 631) {
            int r = k - 624;
            float sacc = 0.f;
            for (int d = 0; d < 64; d++)
                sacc = fmaf(W_lin[j * 448 + r * 64 + d], b_edge[d], sacc);
            v = sacc;
        } else {
            v = 0.f;
        }
        Bp[((k >> 3) * 64 + j) * 8 + (k & 7)] = (bf16_t)v;
    }

    // ---- scatter: 4 edges / thread, int4-coalesced (400000 threads) ----
    if (t < E_EDGES / 4) {
        const int4* ep = (const int4*)(el + (size_t)t * 12);  // t*48B, 16B-aligned
        int4 q0 = ep[0], q1 = ep[1], q2 = ep[2];
        float4 w4 = *(const float4*)(wgt + (size_t)t * 4);
        const int e = t * 4;
        const int srcs[4] = {q0.x, q0.w, q1.z, q2.y};
        const int dsts[4] = {q0.y, q1.x, q1.w, q2.z};
        const int rels[4] = {q0.z, q1.y, q2.x, q2.w};
        const float ws[4] = {w4.x, w4.y, w4.z, w4.w};
        int slot[4];
#pragma unroll
        for (int i = 0; i < 4; i++)
            slot[i] = atomicAdd(&cnt[dsts[i] * CSTR], 1);
#pragma unroll
        for (int i = 0; i < 4; i++) {
            unsigned u0 = (unsigned)srcs[i] | ((unsigned)rels[i] << 17)
                        | ((unsigned)((e + i) & 0xFFF) << 20);
            unsigned u1 = ((unsigned)(e + i) >> 12)
                        | (__float_as_uint(ws[i]) & 0xFFFFFE00u);
            if (slot[i] < CAP)   // safety guard (was latent OOB in node-major)
                recs8[(size_t)slot[i] * N_NODES + dsts[i]] = ((u64)u1 << 32) | u0;
        }
    }
}

// ---------------- fused gather/segment-sum + MFMA GEMM ----------------------
// Stage 1 (verified R7): per node, rel-sort records in-register (7 ballots ->
// rank = prefix[rel] + mbcnt -> ds_permute), pad with (rel=7,w=0) dummies,
// then guard-free CHUNK=16 issue/consume windows (arrays stay in registers).
// Window load now slot-major: recs8[lane * N + n] (8x line reuse per block).

__global__ __launch_bounds__(256, 6) void k_main(
    const bf16_t* __restrict__ xb, const float* __restrict__ ef,
    const float* __restrict__ b_lin, const float* __restrict__ b_self,
    const int* __restrict__ cnt, const u64* __restrict__ recs8,
    const bf16_t* __restrict__ Bp, float* __restrict__ out)
{
    __shared__ __align__(16) unsigned char A[16 * AROWB];  // 20 KB exactly
    const int wave = threadIdx.x >> 6;
    const int lane = threadIdx.x & 63;
    const int lef  = lane & 15;
    const int nodeBase = blockIdx.x * 16;
    const int n0 = nodeBase + wave * 4;

    // prefetch degrees (scalar via RFL), record windows, self rows; pre-zero
    // all accumulation regions (msg rows bytes 0..895; F/sw/pad 1024..1279).
    int md[4];
    u64 rw[4];
#pragma unroll
    for (int i = 0; i < 4; i++) {
        const int row = wave * 4 + i;
        md[i] = RFL(min(cnt[(n0 + i) * CSTR], CAP));
        rw[i] = (lane < md[i]) ? recs8[(size_t)lane * N_NODES + (n0 + i)] : 0ull;
        *(bf16_t*)(A + ASWZ(row, (448 + lane) * 2)) = xb[(n0 + i) * 64 + lane];
        uint4 z = {0u, 0u, 0u, 0u};
        if (lane < 56) *(uint4*)(A + ASWZ(row, lane * 16)) = z;
        if (lane < 16) *(uint4*)(A + ASWZ(row, 1024 + lane * 16)) = z;
    }

#pragma unroll
    for (int i = 0; i < 4; i++) {
        const int row = wave * 4 + i;
        const int m = md[i];
        if (m == 0) continue;                        // wave-uniform skip
        const int u0v = (int)(unsigned)rw[i];
        const int u1v = (int)(unsigned)(rw[i] >> 32);
        const int relv = ((unsigned)u0v >> 17) & 7;
        const bool valid = lane < m;

        // ---- in-register sort by rel (verified R6/R7) ----
        u64 g0 = __ballot(valid && relv == 0);
        u64 g1 = __ballot(valid && relv == 1);
        u64 g2 = __ballot(valid && relv == 2);
        u64 g3 = __ballot(valid && relv == 3);
        u64 g4 = __ballot(valid && relv == 4);
        u64 g5 = __ballot(valid && relv == 5);
        u64 g6 = __ballot(valid && relv == 6);
        const int c0 = __builtin_popcountll(g0), c1 = __builtin_popcountll(g1);
        const int c2 = __builtin_popcountll(g2), c3 = __builtin_popcountll(g3);
        const int c4 = __builtin_popcountll(g4), c5 = __builtin_popcountll(g5);
        const int p0 = 0, p1 = c0, p2 = p1 + c1, p3 = p2 + c2;
        const int p4 = p3 + c3, p5 = p4 + c4, p6 = p5 + c5;
        const bool b0 = relv & 1, b1 = relv & 2, b2 = relv & 4;
        u64 t0 = b0 ? g1 : g0, t1 = b0 ? g3 : g2, t2 = b0 ? g5 : g4, t3 = g6;
        u64 sA = b1 ? t1 : t0, sB = b1 ? t3 : t2;
        u64 mm = b2 ? sB : sA;
        int pa = b0 ? p1 : p0, pb = b0 ? p3 : p2, pc = b0 ? p5 : p4, pd = p6;
        int pe_ = b1 ? pb : pa, pf_ = b1 ? pd : pc;
        int pfx = b2 ? pf_ : pe_;
        int rig = __builtin_amdgcn_mbcnt_hi((unsigned)(mm >> 32),
                  __builtin_amdgcn_mbcnt_lo((unsigned)mm, 0));
        int rank = valid ? (pfx + rig) : lane;       // bijective 0..63
        // dummy payload for pad positions: rel=7, w=0, src=0, e=0
        const int pv0 = valid ? u0v : (7 << 17);
        const int pv1 = valid ? u1v : 0;
        const int su0 = __builtin_amdgcn_ds_permute(rank * 4, pv0);
        const int su1 = __builtin_amdgcn_ds_permute(rank * 4, pv1);

        // ---- guard-free chunked issue/consume over the padded stream ----
        float a = 0.f, F = 0.f, sw_ = 0.f;
        int cur = -1;
        for (int base = 0; base < m; base += CHUNK) {
            unsigned short xv[CHUNK];
            float ev[CHUNK], wk[CHUNK];
            int rk[CHUNK];
#pragma unroll
            for (int k = 0; k < CHUNK; k++) {        // unconditional: regs
                const int uu0 = RL(su0, base + k);
                const int uu1 = RL(su1, base + k);
                const int src = uu0 & 0x1FFFF;
                const int e   = (int)(((unsigned)uu0) >> 20)
                              | ((uu1 & 0x1FF) << 12);
                rk[k] = (int)((((unsigned)uu0) >> 17) & 7);
                wk[k] = __uint_as_float((unsigned)uu1 & 0xFFFFFE00u);
                xv[k] = *(const unsigned short*)(xb + ((size_t)src << 6) + lane);
                ev[k] = ef[(size_t)e * EDIM + lef];
            }
#pragma unroll
            for (int k = 0; k < CHUNK; k++) {        // unconditional: regs
                if (rk[k] != cur && rk[k] != 7) {    // scalar rel boundary
                    if (cur >= 0) {
                        *(bf16_t*)(A + ASWZ(row, (cur * 64 + lane) * 2)) = (bf16_t)a;
                        if (lane < EDIM)
                            *(bf16_t*)(A + ASWZ(row, (512 + cur * EDIM + lane) * 2)) = (bf16_t)F;
                        if (lane == 0)
                            *(bf16_t*)(A + ASWZ(row, (624 + cur) * 2)) = (bf16_t)sw_;
                    }
                    a = 0.f; F = 0.f; sw_ = 0.f; cur = rk[k];
                }
                const float xf = __uint_as_float(((unsigned)xv[k]) << 16);
                a   = fmaf(wk[k], xf,    a);         // dummies: w=0, exact no-op
                F   = fmaf(wk[k], ev[k], F);
                sw_ += wk[k];
            }
        }
        // final flush (m>0 guarantees cur>=0)
        *(bf16_t*)(A + ASWZ(row, (cur * 64 + lane) * 2)) = (bf16_t)a;
        if (lane < EDIM)
            *(bf16_t*)(A + ASWZ(row, (512 + cur * EDIM + lane) * 2)) = (bf16_t)F;
        if (lane == 0)
            *(bf16_t*)(A + ASWZ(row, (624 + cur) * 2)) = (bf16_t)sw_;
    }
    __syncthreads();

    // stage 2: MFMA over K=640 (swizzled A reads; verified R4/R6/R7)
    const int quad = lane >> 4;
    const int l15  = lane & 15;
    const unsigned abase = (unsigned)l15 * AROWB;
    const unsigned aswz  = (unsigned)((l15 & 7) << 4);
    f32x4 c = {0.f, 0.f, 0.f, 0.f};
#pragma unroll
    for (int s2i = 0; s2i < KTOT / 32; s2i++) {
        bf16x8 av = *(const bf16x8*)(A + abase
                     + (((unsigned)(s2i * 64 + quad * 16)) ^ aswz));
        bf16x8 bv = *(const bf16x8*)(Bp + (((s2i * 4 + quad) * 64) + wave * 16 + l15) * 8);
        c = __builtin_amdgcn_mfma_f32_16x16x32_bf16(av, bv, c, 0, 0, 0);
    }
    const int j = wave * 16 + l15;
    const float bias = b_lin[j] + b_self[j];
#pragma unroll
    for (int q = 0; q < 4; q++) {
        const int n = nodeBase + quad * 4 + q;
        float v = c[q] + bias;
        out[n * 64 + j] = v > 0.f ? v : 0.f;
    }
}

// ---------------- launch ----------------------------------------------------

extern "C" void kernel_launch(void* const* d_in, const int* in_sizes, int n_in,
                              void* d_out, int out_size, void* d_ws, size_t ws_size,
                              hipStream_t stream) {
    const float* x      = (const float*)d_in[0];
    const int*   el     = (const int*)  d_in[1];
    const float* wgt    = (const float*)d_in[2];
    const float* ef     = (const float*)d_in[3];
    const float* W_lin  = (const float*)d_in[4];
    const float* b_lin  = (const float*)d_in[5];
    const float* W_self = (const float*)d_in[6];
    const float* b_self = (const float*)d_in[7];
    const float* W_edge = (const float*)d_in[8];
    const float* b_edge = (const float*)d_in[9];
    float* out = (float*)d_out;

    // workspace: recs8(44.8M, slot-major) | cnt(6.4M padded) | xb(12.8M) | Bp(80K)
    u64*    recs8 = (u64*)d_ws;
    int*    cnt   = (int*)(recs8 + (size_t)N_NODES * CAP);
    bf16_t* xb    = (bf16_t*)(cnt + (size_t)N_NODES * CSTR);
    bf16_t* Bp    = xb + (size_t)N_NODES * 64;

    hipMemsetAsync(cnt, 0, (size_t)N_NODES * CSTR * sizeof(int), stream);
    k_pre <<<1563, 256, 0, stream>>>(x, el, wgt, W_lin, W_self, W_edge, b_edge,
                                     cnt, xb, Bp, recs8);
    k_main<<<N_NODES / 16, 256, 0, stream>>>(xb, ef, b_lin, b_self,
                                             cnt, recs8, Bp, out);
}